// Round 4
// baseline (2667.775 us; speedup 1.0000x reference)
//
#include <hip/hip_runtime.h>
#include <hip/hip_bf16.h>
#include <hip/hip_fp16.h>

typedef __attribute__((ext_vector_type(8))) _Float16 half8;
typedef __attribute__((ext_vector_type(4))) _Float16 half4v;
typedef __attribute__((ext_vector_type(4))) float f32x4;

#define T_LEN 2048
#define NCH 128
#define CHS 16

__device__ __forceinline__ float rcpf_(float x){ return __builtin_amdgcn_rcpf(x); }

__device__ __forceinline__ half4v pack4(float4 a){
  half4v r;
  r[0]=(_Float16)a.x; r[1]=(_Float16)a.y; r[2]=(_Float16)a.z; r[3]=(_Float16)a.w;
  return r;
}

// ---------------------------------------------------------------------------
// Kernel 1: gate table = emb @ Wih.T + bias, per direction. [2][4096][512] f32.
// mfma_f32_16x16x16f16 canonical layout: A/B lane l: m(or n)=l&15, k=4*(l>>4)+j.
// C/D: col=l&15, row=4*(l>>4)+reg.
__global__ __launch_bounds__(512) void k_table(const float* __restrict__ emb,
    const float* __restrict__ Wih_f, const float* __restrict__ b_f,
    const float* __restrict__ Wih_b, const float* __restrict__ b_b,
    float* __restrict__ table){
  const int dir = blockIdx.x & 1, vt = blockIdx.x >> 1;
  const float* Wih  = dir ? Wih_b : Wih_f;
  const float* bias = dir ? b_b  : b_f;
  const int w = threadIdx.x >> 6, l = threadIdx.x & 63;
  const int lA = l & 15, hi = l >> 4;

  half4v wf[4][8];
#pragma unroll
  for (int g = 0; g < 4; ++g)
#pragma unroll
    for (int kb = 0; kb < 8; ++kb){
      const size_t base = (size_t)(g*128 + 16*w + lA)*128 + kb*16 + 4*hi;
      wf[g][kb] = pack4(*reinterpret_cast<const float4*>(Wih + base));
    }
  const int v0 = vt*16;
  half4v bfr[8];
#pragma unroll
  for (int kb = 0; kb < 8; ++kb){
    const size_t base = (size_t)(v0 + lA)*128 + kb*16 + 4*hi;
    bfr[kb] = pack4(*reinterpret_cast<const float4*>(emb + base));
  }
  f32x4 acc[4];
#pragma unroll
  for (int g = 0; g < 4; ++g)
    acc[g] = *reinterpret_cast<const f32x4*>(bias + g*128 + 16*w + 4*hi);
#pragma unroll
  for (int kb = 0; kb < 8; ++kb)
#pragma unroll
    for (int g = 0; g < 4; ++g)
      acc[g] = __builtin_amdgcn_mfma_f32_16x16x16f16(wf[g][kb], bfr[kb], acc[g], 0, 0, 0);
  float* outp = table + ((size_t)dir*4096 + v0 + lA)*512 + 16*w + 4*hi;
#pragma unroll
  for (int g = 0; g < 4; ++g)
    *reinterpret_cast<f32x4*>(outp + g*128) = acc[g];
}

// ---------------------------------------------------------------------------
// LSTM epilogue: c' = sig(f)*c + sig(i)*tanh(g); h = sig(o)*tanh(c')
__device__ __forceinline__ void epi_step(float iv, float fv, float gv, float ov,
                                         float& c, float& h){
  float Ae = __expf(-iv);
  float Be = __expf(2.f*gv);
  float st = (Be - 1.f) * rcpf_((1.f + Ae)*(Be + 1.f));
  float Fe = __expf(-fv);
  float cn = rcpf_(1.f + Fe)*c + st;
  c = cn;
  float Oe = __expf(-ov);
  float Ce = __expf(2.f*cn);
  h = (Ce - 1.f) * rcpf_((1.f + Oe)*(Ce + 1.f));
}

// ---------------------------------------------------------------------------
// Kernel 2: persistent BiLSTM, hh-recurrence (ih part gathered from table).
// grid = 8 blocks (dir*4 + chain), 512 threads = 8 waves.
// Wave w: units [16w,16w+16) all 4 gates; == K-block kb=w of next h fragment.
// Lane: batch=l&15, units 16w+4*(l>>4)+r.
__global__ __launch_bounds__(512, 2) void k_lstm(
    const float* __restrict__ Whh_f, const float* __restrict__ Whh_b,
    const int* __restrict__ x, const float* __restrict__ table,
    _Float16* __restrict__ hcat){
  const int dir = blockIdx.x >> 2;
  const int chain = blockIdx.x & 3;
  const float* Whh = dir ? Whh_b : Whh_f;
  const float* tbl = table + (size_t)dir*4096*512;
  const int w  = threadIdx.x >> 6;
  const int l  = threadIdx.x & 63;
  const int lA = l & 15;
  const int hi = l >> 4;

  half4v whh[4][8];
#pragma unroll
  for (int g = 0; g < 4; ++g)
#pragma unroll
    for (int kb = 0; kb < 8; ++kb){
      const size_t base = (size_t)(g*128 + 16*w + lA)*128 + kb*16 + 4*hi;
      whh[g][kb] = pack4(*reinterpret_cast<const float4*>(Whh + base));
    }

  __shared__ __align__(16) _Float16 hbuf[2][8][64][4];
  reinterpret_cast<int4*>(&hbuf[0][0][0][0])[threadIdx.x] = make_int4(0,0,0,0);
  __syncthreads();

  const int b = chain*16 + lA;
  const int* xrow = x + (size_t)b*T_LEN;
  _Float16* hgbase = hcat + (size_t)b*256 + dir*128 + 16*w + 4*hi;
  _Float16* ldsw0 = &hbuf[0][w][l][0];
  _Float16* ldsw1 = &hbuf[1][w][l][0];
  const int toff = 16*w + 4*hi;

  f32x4 tb_c[4], tb_n[4];
  int idx_n;
  {
    const int tx0 = dir ? (T_LEN-1) : 0;
    const int idx0 = xrow[tx0];
    const float* tp = tbl + (size_t)idx0*512 + toff;
#pragma unroll
    for (int g = 0; g < 4; ++g) tb_c[g] = *reinterpret_cast<const f32x4*>(tp + g*128);
    idx_n = xrow[dir ? (T_LEN-2) : 1];
  }
  float cc0=0.f, cc1=0.f, cc2=0.f, cc3=0.f;

  for (int t = 0; t < T_LEN; ++t){
    const int tx = dir ? (T_LEN-1-t) : t;
    if (t + 1 < T_LEN){
      const float* tp = tbl + (size_t)idx_n*512 + toff;
#pragma unroll
      for (int g = 0; g < 4; ++g) tb_n[g] = *reinterpret_cast<const f32x4*>(tp + g*128);
    }
    if (t + 2 < T_LEN) idx_n = xrow[dir ? (T_LEN-3-t) : (t+2)];

    const int pb = t & 1;
    half4v ah[8];
#pragma unroll
    for (int kb = 0; kb < 8; ++kb)
      ah[kb] = *reinterpret_cast<const half4v*>(&hbuf[pb][kb][l][0]);

    f32x4 acc[4];
#pragma unroll
    for (int g = 0; g < 4; ++g) acc[g] = tb_c[g];
#pragma unroll
    for (int kb = 0; kb < 8; ++kb)
#pragma unroll
      for (int g = 0; g < 4; ++g)
        acc[g] = __builtin_amdgcn_mfma_f32_16x16x16f16(whh[g][kb], ah[kb], acc[g], 0, 0, 0);

    float hv0, hv1, hv2, hv3;
    epi_step(acc[0][0], acc[1][0], acc[2][0], acc[3][0], cc0, hv0);
    epi_step(acc[0][1], acc[1][1], acc[2][1], acc[3][1], cc1, hv1);
    epi_step(acc[0][2], acc[1][2], acc[2][2], acc[3][2], cc2, hv2);
    epi_step(acc[0][3], acc[1][3], acc[2][3], acc[3][3], cc3, hv3);

    half4v hp;
    hp[0]=(_Float16)hv0; hp[1]=(_Float16)hv1; hp[2]=(_Float16)hv2; hp[3]=(_Float16)hv3;
    *reinterpret_cast<half4v*>((t & 1) ? ldsw0 : ldsw1) = hp;   // buf (t+1)&1
    *reinterpret_cast<half4v*>(hgbase + (size_t)tx*16384) = hp;
#pragma unroll
    for (int g = 0; g < 4; ++g) tb_c[g] = tb_n[g];
    asm volatile("s_waitcnt lgkmcnt(0)" ::: "memory");
    __builtin_amdgcn_sched_barrier(0);
    __builtin_amdgcn_s_barrier();        // no vmcnt drain: prefetches stay in flight
    __builtin_amdgcn_sched_barrier(0);
  }
}

// ---------------------------------------------------------------------------
// Kernel 3: CRF chunk transition matrices (log-semiring chain product).
// One wave per (chunk k, batch b); lane = i*8+jc holds P[i][jc].
__global__ __launch_bounds__(256) void k_crfchunk(const _Float16* __restrict__ hcat,
    const float* __restrict__ fc_w, const float* __restrict__ fc_b,
    const float* __restrict__ trans, float* __restrict__ chunkP){
  const int wv = threadIdx.x >> 6;
  const int l  = threadIdx.x & 63;
  const int task = blockIdx.x*4 + wv;   // k*64 + b
  const int k = task >> 6;
  const int b = task & 63;
  const int i = l >> 3, jc = l & 7;
  float trC[8];
#pragma unroll
  for (int kk = 0; kk < 8; ++kk) trC[kk] = trans[kk*8 + jc];
  const float tii = trans[l];
  float wreg[32];
#pragma unroll
  for (int q = 0; q < 32; ++q) wreg[q] = fc_w[jc*256 + i*32 + q];
  const float fcb = fc_b[jc];
  const int tstart = 1 + k*CHS;
  const int len = (CHS < T_LEN - tstart) ? CHS : (T_LEN - tstart);
  float P = 0.f;
  for (int s = 0; s < len; ++s){
    const int t = tstart + s;
    const _Float16* hp = hcat + ((size_t)t*64 + b)*256 + i*32;
    float dot = 0.f;                       // bias added ONCE after reduction
#pragma unroll
    for (int q8 = 0; q8 < 4; ++q8){
      half8 hv = *reinterpret_cast<const half8*>(hp + q8*8);
#pragma unroll
      for (int j = 0; j < 8; ++j) dot += (float)hv[j] * wreg[q8*8 + j];
    }
    dot += __shfl_xor(dot, 8);
    dot += __shfl_xor(dot, 16);
    dot += __shfl_xor(dot, 32);
    const float em = fcb + dot;
    if (s == 0){
      P = tii + em;
    } else {
      float v[8];
#pragma unroll
      for (int kk = 0; kk < 8; ++kk) v[kk] = __shfl(P, (l & 56) | kk) + trC[kk];
      float m = v[0];
#pragma unroll
      for (int kk = 1; kk < 8; ++kk) m = fmaxf(m, v[kk]);
      float ss = 0.f;
#pragma unroll
      for (int kk = 0; kk < 8; ++kk) ss += __expf(v[kk] - m);
      P = m + __logf(ss) + em;
    }
  }
  chunkP[(size_t)task*64 + l] = P;
}

// ---------------------------------------------------------------------------
// Kernel 4: fold alpha0 through 128 chunk matrices, LSE with end.
__global__ __launch_bounds__(512) void k_crffinal(const _Float16* __restrict__ hcat,
    const float* __restrict__ fc_w, const float* __restrict__ fc_b,
    const float* __restrict__ trans, const float* __restrict__ startv,
    const float* __restrict__ endv, const float* __restrict__ chunkP,
    float* __restrict__ out){
  const int tid = threadIdx.x;
  const int b = tid >> 3, jc = tid & 7;
  const int l = tid & 63;
  float em = fc_b[jc];
  const _Float16* hp = hcat + (size_t)b*256;   // t = 0
  const float* wr = fc_w + jc*256;
#pragma unroll
  for (int q = 0; q < 32; ++q){
    half8 hv = *reinterpret_cast<const half8*>(hp + q*8);
#pragma unroll
    for (int j = 0; j < 8; ++j) em += (float)hv[j] * wr[q*8 + j];
  }
  float alpha = startv[jc] + em;
  for (int k = 0; k < NCH; ++k){
    const float* pk = chunkP + ((size_t)k*64 + b)*64;
    float v[8];
#pragma unroll
    for (int kk = 0; kk < 8; ++kk) v[kk] = __shfl(alpha, (l & 56) | kk) + pk[kk*8 + jc];
    float m = v[0];
#pragma unroll
    for (int kk = 1; kk < 8; ++kk) m = fmaxf(m, v[kk]);
    float ss = 0.f;
#pragma unroll
    for (int kk = 0; kk < 8; ++kk) ss += __expf(v[kk] - m);
    alpha = m + __logf(ss);
  }
  float vf = alpha + endv[jc];
  float m = vf;
  m = fmaxf(m, __shfl_xor(m, 1));
  m = fmaxf(m, __shfl_xor(m, 2));
  m = fmaxf(m, __shfl_xor(m, 4));
  float e = __expf(vf - m);
  e += __shfl_xor(e, 1);
  e += __shfl_xor(e, 2);
  e += __shfl_xor(e, 4);
  if (jc == 0) out[b] = m + __logf(e);
}

// ---------------------------------------------------------------------------
extern "C" void kernel_launch(void* const* d_in, const int* in_sizes, int n_in,
                              void* d_out, int out_size, void* d_ws, size_t ws_size,
                              hipStream_t stream){
  const int*   x     = (const int*)d_in[0];
  const float* emb   = (const float*)d_in[1];
  const float* Wih_f = (const float*)d_in[2];
  const float* Whh_f = (const float*)d_in[3];
  const float* b_f   = (const float*)d_in[4];
  const float* Wih_b = (const float*)d_in[5];
  const float* Whh_b = (const float*)d_in[6];
  const float* b_b   = (const float*)d_in[7];
  const float* fc_w  = (const float*)d_in[8];
  const float* fc_b  = (const float*)d_in[9];
  const float* trans = (const float*)d_in[10];
  const float* startp= (const float*)d_in[11];
  const float* endp  = (const float*)d_in[12];
  float* out = (float*)d_out;

  const size_t off_tbl  = 0;
  const size_t off_hcat = 16777216;               // 2*4096*512*4
  const size_t off_chk  = 16777216 + 67108864;    // + 2048*64*256*2
  const size_t need     = off_chk + 2097152;      // + 128*64*64*4
  if (ws_size < need){
    (void)hipMemsetAsync(d_out, 0, 64*sizeof(float), stream);
    return;
  }
  float* table  = (float*)((char*)d_ws + off_tbl);
  _Float16* hcat = (_Float16*)((char*)d_ws + off_hcat);
  float* chunkP  = (float*)((char*)d_ws + off_chk);

  k_table<<<512, 512, 0, stream>>>(emb, Wih_f, b_f, Wih_b, b_b, table);
  k_lstm<<<8, 512, 0, stream>>>(Whh_f, Whh_b, x, table, hcat);
  k_crfchunk<<<2048, 256, 0, stream>>>(hcat, fc_w, fc_b, trans, chunkP);
  k_crffinal<<<1, 512, 0, stream>>>(hcat, fc_w, fc_b, trans, startp, endp, chunkP, out);
}

// Round 5
// 2621.081 us; speedup vs baseline: 1.0178x; 1.0178x over previous
//
#include <hip/hip_runtime.h>
#include <hip/hip_bf16.h>
#include <hip/hip_fp16.h>

typedef __attribute__((ext_vector_type(8))) _Float16 half8;
typedef __attribute__((ext_vector_type(4))) _Float16 half4v;
typedef __attribute__((ext_vector_type(4))) float f32x4;

#define T_LEN 2048
#define NCH 128
#define CHS 16

__device__ __forceinline__ float rcpf_(float x){ return __builtin_amdgcn_rcpf(x); }

__device__ __forceinline__ half4v pack4(float4 a){
  half4v r;
  r[0]=(_Float16)a.x; r[1]=(_Float16)a.y; r[2]=(_Float16)a.z; r[3]=(_Float16)a.w;
  return r;
}

// ---------------------------------------------------------------------------
// Kernel 1: gate table = emb @ Wih.T + bias, per direction.
// Layout: [dir][v][w(8)][hi(4)][g(4)][4] f32  (each (v,w,hi) = 64B contiguous)
// mfma_f32_16x16x16f16 canonical: A/B lane l: m(n)=l&15, k=4*(l>>4)+j.
// C/D: col=l&15, row=4*(l>>4)+reg.
__global__ __launch_bounds__(512) void k_table(const float* __restrict__ emb,
    const float* __restrict__ Wih_f, const float* __restrict__ b_f,
    const float* __restrict__ Wih_b, const float* __restrict__ b_b,
    float* __restrict__ table){
  const int dir = blockIdx.x & 1, vt = blockIdx.x >> 1;
  const float* Wih  = dir ? Wih_b : Wih_f;
  const float* bias = dir ? b_b  : b_f;
  const int w = threadIdx.x >> 6, l = threadIdx.x & 63;
  const int lA = l & 15, hi = l >> 4;

  half4v wf[4][8];
#pragma unroll
  for (int g = 0; g < 4; ++g)
#pragma unroll
    for (int kb = 0; kb < 8; ++kb){
      const size_t base = (size_t)(g*128 + 16*w + lA)*128 + kb*16 + 4*hi;
      wf[g][kb] = pack4(*reinterpret_cast<const float4*>(Wih + base));
    }
  const int v0 = vt*16;
  half4v bfr[8];
#pragma unroll
  for (int kb = 0; kb < 8; ++kb){
    const size_t base = (size_t)(v0 + lA)*128 + kb*16 + 4*hi;
    bfr[kb] = pack4(*reinterpret_cast<const float4*>(emb + base));
  }
  f32x4 acc[4];
#pragma unroll
  for (int g = 0; g < 4; ++g)
    acc[g] = *reinterpret_cast<const f32x4*>(bias + g*128 + 16*w + 4*hi);
#pragma unroll
  for (int kb = 0; kb < 8; ++kb)
#pragma unroll
    for (int g = 0; g < 4; ++g)
      acc[g] = __builtin_amdgcn_mfma_f32_16x16x16f16(wf[g][kb], bfr[kb], acc[g], 0, 0, 0);
  // new contiguous layout: ((dir*4096+v)*8 + w)*4 + hi, 16 floats per cell
  float* outp = table + ((((size_t)dir*4096 + v0 + lA)*8 + w)*4 + hi)*16;
#pragma unroll
  for (int g = 0; g < 4; ++g)
    *reinterpret_cast<f32x4*>(outp + g*4) = acc[g];
}

// ---------------------------------------------------------------------------
// LSTM epilogue: c' = sig(f)*c + sig(i)*tanh(g); h = sig(o)*tanh(c')
__device__ __forceinline__ void epi_step(float iv, float fv, float gv, float ov,
                                         float& c, float& h){
  float Ae = __expf(-iv);
  float Be = __expf(2.f*gv);
  float st = (Be - 1.f) * rcpf_((1.f + Ae)*(Be + 1.f));
  float Fe = __expf(-fv);
  float cn = rcpf_(1.f + Fe)*c + st;
  c = cn;
  float Oe = __expf(-ov);
  float Ce = __expf(2.f*cn);
  h = (Ce - 1.f) * rcpf_((1.f + Oe)*(Ce + 1.f));
}

// ---------------------------------------------------------------------------
// Kernel 2: persistent BiLSTM, unroll-2 with depth-2 table prefetch.
// grid = 8 blocks (dir*4 + chain), 512 threads = 8 waves.
// Wave w: units [16w,16w+16) all gates; == K-block kb=w of next h fragment.
__global__ __launch_bounds__(512, 2) void k_lstm(
    const float* __restrict__ Whh_f, const float* __restrict__ Whh_b,
    const int* __restrict__ x, const float* __restrict__ table,
    _Float16* __restrict__ hcat){
  const int dir = blockIdx.x >> 2;
  const int chain = blockIdx.x & 3;
  const float* Whh = dir ? Whh_b : Whh_f;
  const float* tbl = table + (size_t)dir*4096*512;
  const int w  = threadIdx.x >> 6;
  const int l  = threadIdx.x & 63;
  const int lA = l & 15;
  const int hi = l >> 4;

  half4v whh[4][8];
#pragma unroll
  for (int g = 0; g < 4; ++g)
#pragma unroll
    for (int kb = 0; kb < 8; ++kb){
      const size_t base = (size_t)(g*128 + 16*w + lA)*128 + kb*16 + 4*hi;
      whh[g][kb] = pack4(*reinterpret_cast<const float4*>(Whh + base));
    }

  __shared__ __align__(16) _Float16 hbuf[2][8][64][4];
  reinterpret_cast<int4*>(&hbuf[0][0][0][0])[threadIdx.x] = make_int4(0,0,0,0);
  __syncthreads();

  const int b = chain*16 + lA;
  const int* xrow = x + (size_t)b*T_LEN;
  _Float16* hgbase = hcat + (size_t)b*256 + dir*128 + 16*w + 4*hi;
  _Float16* ldsw0 = &hbuf[0][w][l][0];
  _Float16* ldsw1 = &hbuf[1][w][l][0];
  const int seg = (w*4 + hi)*16;          // lane's 64B segment within a row

  // prologue: issue depth-2 prefetch
  f32x4 tbA[4], tbB[4];
  int idxA2, idxB2;
  {
    const int i0 = xrow[dir ? 2047 : 0];
    const int i1 = xrow[dir ? 2046 : 1];
    const float* pA = tbl + (size_t)i0*512 + seg;
    const float* pB = tbl + (size_t)i1*512 + seg;
#pragma unroll
    for (int g = 0; g < 4; ++g) tbA[g] = *reinterpret_cast<const f32x4*>(pA + g*4);
#pragma unroll
    for (int g = 0; g < 4; ++g) tbB[g] = *reinterpret_cast<const f32x4*>(pB + g*4);
    idxA2 = xrow[dir ? 2045 : 2];
    idxB2 = xrow[dir ? 2044 : 3];
  }
  float cc0=0.f, cc1=0.f, cc2=0.f, cc3=0.f;

  for (int tt = 0; tt < T_LEN; tt += 2){
    // ================= even step t=tt : read hbuf[0], write hbuf[1] ========
    {
      half4v ah[8];
#pragma unroll
      for (int kb = 0; kb < 8; ++kb)
        ah[kb] = *reinterpret_cast<const half4v*>(&hbuf[0][kb][l][0]);
      f32x4 acc[4];
#pragma unroll
      for (int g = 0; g < 4; ++g)
        acc[g] = __builtin_amdgcn_mfma_f32_16x16x16f16(whh[g][0], ah[0], tbA[g], 0, 0, 0);
      // reissue tbA <- gates(t+2)
      {
        const float* pA = tbl + (size_t)idxA2*512 + seg;
#pragma unroll
        for (int g = 0; g < 4; ++g) tbA[g] = *reinterpret_cast<const f32x4*>(pA + g*4);
        const int tn = (tt+4 < T_LEN) ? tt+4 : T_LEN-1;
        idxA2 = xrow[dir ? (T_LEN-1-tn) : tn];
      }
#pragma unroll
      for (int kb = 1; kb < 8; ++kb)
#pragma unroll
        for (int g = 0; g < 4; ++g)
          acc[g] = __builtin_amdgcn_mfma_f32_16x16x16f16(whh[g][kb], ah[kb], acc[g], 0, 0, 0);

      float hv0, hv1, hv2, hv3;
      epi_step(acc[0][0], acc[1][0], acc[2][0], acc[3][0], cc0, hv0);
      epi_step(acc[0][1], acc[1][1], acc[2][1], acc[3][1], cc1, hv1);
      epi_step(acc[0][2], acc[1][2], acc[2][2], acc[3][2], cc2, hv2);
      epi_step(acc[0][3], acc[1][3], acc[2][3], acc[3][3], cc3, hv3);
      half4v hp;
      hp[0]=(_Float16)hv0; hp[1]=(_Float16)hv1; hp[2]=(_Float16)hv2; hp[3]=(_Float16)hv3;
      *reinterpret_cast<half4v*>(ldsw1) = hp;
      const int tx = dir ? (T_LEN-1-tt) : tt;
      *reinterpret_cast<half4v*>(hgbase + (size_t)tx*16384) = hp;
      asm volatile("s_waitcnt lgkmcnt(0)" ::: "memory");
      __builtin_amdgcn_sched_barrier(0);
      __builtin_amdgcn_s_barrier();
      __builtin_amdgcn_sched_barrier(0);
    }
    // ================= odd step t=tt+1 : read hbuf[1], write hbuf[0] =======
    {
      half4v ah[8];
#pragma unroll
      for (int kb = 0; kb < 8; ++kb)
        ah[kb] = *reinterpret_cast<const half4v*>(&hbuf[1][kb][l][0]);
      f32x4 acc[4];
#pragma unroll
      for (int g = 0; g < 4; ++g)
        acc[g] = __builtin_amdgcn_mfma_f32_16x16x16f16(whh[g][0], ah[0], tbB[g], 0, 0, 0);
      // reissue tbB <- gates(t+3)
      {
        const float* pB = tbl + (size_t)idxB2*512 + seg;
#pragma unroll
        for (int g = 0; g < 4; ++g) tbB[g] = *reinterpret_cast<const f32x4*>(pB + g*4);
        const int tn = (tt+5 < T_LEN) ? tt+5 : T_LEN-1;
        idxB2 = xrow[dir ? (T_LEN-1-tn) : tn];
      }
#pragma unroll
      for (int kb = 1; kb < 8; ++kb)
#pragma unroll
        for (int g = 0; g < 4; ++g)
          acc[g] = __builtin_amdgcn_mfma_f32_16x16x16f16(whh[g][kb], ah[kb], acc[g], 0, 0, 0);

      float hv0, hv1, hv2, hv3;
      epi_step(acc[0][0], acc[1][0], acc[2][0], acc[3][0], cc0, hv0);
      epi_step(acc[0][1], acc[1][1], acc[2][1], acc[3][1], cc1, hv1);
      epi_step(acc[0][2], acc[1][2], acc[2][2], acc[3][2], cc2, hv2);
      epi_step(acc[0][3], acc[1][3], acc[2][3], acc[3][3], cc3, hv3);
      half4v hp;
      hp[0]=(_Float16)hv0; hp[1]=(_Float16)hv1; hp[2]=(_Float16)hv2; hp[3]=(_Float16)hv3;
      *reinterpret_cast<half4v*>(ldsw0) = hp;
      const int tx = dir ? (T_LEN-2-tt) : tt+1;
      *reinterpret_cast<half4v*>(hgbase + (size_t)tx*16384) = hp;
      asm volatile("s_waitcnt lgkmcnt(0)" ::: "memory");
      __builtin_amdgcn_sched_barrier(0);
      __builtin_amdgcn_s_barrier();
      __builtin_amdgcn_sched_barrier(0);
    }
  }
}

// ---------------------------------------------------------------------------
// Kernel 3: CRF chunk transition matrices (log-semiring chain product).
__global__ __launch_bounds__(256) void k_crfchunk(const _Float16* __restrict__ hcat,
    const float* __restrict__ fc_w, const float* __restrict__ fc_b,
    const float* __restrict__ trans, float* __restrict__ chunkP){
  const int wv = threadIdx.x >> 6;
  const int l  = threadIdx.x & 63;
  const int task = blockIdx.x*4 + wv;   // k*64 + b
  const int k = task >> 6;
  const int b = task & 63;
  const int i = l >> 3, jc = l & 7;
  float trC[8];
#pragma unroll
  for (int kk = 0; kk < 8; ++kk) trC[kk] = trans[kk*8 + jc];
  const float tii = trans[l];
  float wreg[32];
#pragma unroll
  for (int q = 0; q < 32; ++q) wreg[q] = fc_w[jc*256 + i*32 + q];
  const float fcb = fc_b[jc];
  const int tstart = 1 + k*CHS;
  const int len = (CHS < T_LEN - tstart) ? CHS : (T_LEN - tstart);
  float P = 0.f;
  for (int s = 0; s < len; ++s){
    const int t = tstart + s;
    const _Float16* hp = hcat + ((size_t)t*64 + b)*256 + i*32;
    float dot = 0.f;
#pragma unroll
    for (int q8 = 0; q8 < 4; ++q8){
      half8 hv = *reinterpret_cast<const half8*>(hp + q8*8);
#pragma unroll
      for (int j = 0; j < 8; ++j) dot += (float)hv[j] * wreg[q8*8 + j];
    }
    dot += __shfl_xor(dot, 8);
    dot += __shfl_xor(dot, 16);
    dot += __shfl_xor(dot, 32);
    const float em = fcb + dot;
    if (s == 0){
      P = tii + em;
    } else {
      float v[8];
#pragma unroll
      for (int kk = 0; kk < 8; ++kk) v[kk] = __shfl(P, (l & 56) | kk) + trC[kk];
      float m = v[0];
#pragma unroll
      for (int kk = 1; kk < 8; ++kk) m = fmaxf(m, v[kk]);
      float ss = 0.f;
#pragma unroll
      for (int kk = 0; kk < 8; ++kk) ss += __expf(v[kk] - m);
      P = m + __logf(ss) + em;
    }
  }
  chunkP[(size_t)task*64 + l] = P;
}

// ---------------------------------------------------------------------------
// Kernel 4: fold alpha0 through 128 chunk matrices, LSE with end.
__global__ __launch_bounds__(512) void k_crffinal(const _Float16* __restrict__ hcat,
    const float* __restrict__ fc_w, const float* __restrict__ fc_b,
    const float* __restrict__ trans, const float* __restrict__ startv,
    const float* __restrict__ endv, const float* __restrict__ chunkP,
    float* __restrict__ out){
  const int tid = threadIdx.x;
  const int b = tid >> 3, jc = tid & 7;
  const int l = tid & 63;
  float em = fc_b[jc];
  const _Float16* hp = hcat + (size_t)b*256;   // t = 0
  const float* wr = fc_w + jc*256;
#pragma unroll
  for (int q = 0; q < 32; ++q){
    half8 hv = *reinterpret_cast<const half8*>(hp + q*8);
#pragma unroll
    for (int j = 0; j < 8; ++j) em += (float)hv[j] * wr[q*8 + j];
  }
  float alpha = startv[jc] + em;
  for (int k = 0; k < NCH; ++k){
    const float* pk = chunkP + ((size_t)k*64 + b)*64;
    float v[8];
#pragma unroll
    for (int kk = 0; kk < 8; ++kk) v[kk] = __shfl(alpha, (l & 56) | kk) + pk[kk*8 + jc];
    float m = v[0];
#pragma unroll
    for (int kk = 1; kk < 8; ++kk) m = fmaxf(m, v[kk]);
    float ss = 0.f;
#pragma unroll
    for (int kk = 0; kk < 8; ++kk) ss += __expf(v[kk] - m);
    alpha = m + __logf(ss);
  }
  float vf = alpha + endv[jc];
  float m = vf;
  m = fmaxf(m, __shfl_xor(m, 1));
  m = fmaxf(m, __shfl_xor(m, 2));
  m = fmaxf(m, __shfl_xor(m, 4));
  float e = __expf(vf - m);
  e += __shfl_xor(e, 1);
  e += __shfl_xor(e, 2);
  e += __shfl_xor(e, 4);
  if (jc == 0) out[b] = m + __logf(e);
}

// ---------------------------------------------------------------------------
extern "C" void kernel_launch(void* const* d_in, const int* in_sizes, int n_in,
                              void* d_out, int out_size, void* d_ws, size_t ws_size,
                              hipStream_t stream){
  const int*   x     = (const int*)d_in[0];
  const float* emb   = (const float*)d_in[1];
  const float* Wih_f = (const float*)d_in[2];
  const float* Whh_f = (const float*)d_in[3];
  const float* b_f   = (const float*)d_in[4];
  const float* Wih_b = (const float*)d_in[5];
  const float* Whh_b = (const float*)d_in[6];
  const float* b_b   = (const float*)d_in[7];
  const float* fc_w  = (const float*)d_in[8];
  const float* fc_b  = (const float*)d_in[9];
  const float* trans = (const float*)d_in[10];
  const float* startp= (const float*)d_in[11];
  const float* endp  = (const float*)d_in[12];
  float* out = (float*)d_out;

  const size_t off_tbl  = 0;
  const size_t off_hcat = 16777216;               // 2*4096*512*4
  const size_t off_chk  = 16777216 + 67108864;    // + 2048*64*256*2
  const size_t need     = off_chk + 2097152;      // + 128*64*64*4
  if (ws_size < need){
    (void)hipMemsetAsync(d_out, 0, 64*sizeof(float), stream);
    return;
  }
  float* table  = (float*)((char*)d_ws + off_tbl);
  _Float16* hcat = (_Float16*)((char*)d_ws + off_hcat);
  float* chunkP  = (float*)((char*)d_ws + off_chk);

  k_table<<<512, 512, 0, stream>>>(emb, Wih_f, b_f, Wih_b, b_b, table);
  k_lstm<<<8, 512, 0, stream>>>(Whh_f, Whh_b, x, table, hcat);
  k_crfchunk<<<2048, 256, 0, stream>>>(hcat, fc_w, fc_b, trans, chunkP);
  k_crffinal<<<1, 512, 0, stream>>>(hcat, fc_w, fc_b, trans, startp, endp, chunkP, out);
}

// Round 6
// 2602.378 us; speedup vs baseline: 1.0251x; 1.0072x over previous
//
#include <hip/hip_runtime.h>
#include <hip/hip_bf16.h>
#include <hip/hip_fp16.h>

typedef __attribute__((ext_vector_type(8))) _Float16 half8;
typedef __attribute__((ext_vector_type(4))) _Float16 half4v;
typedef __attribute__((ext_vector_type(4))) float f32x4;

#define T_LEN 2048
#define NCH 128
#define CHS 16

__device__ __forceinline__ float rcpf_(float x){ return __builtin_amdgcn_rcpf(x); }

__device__ __forceinline__ half4v pack4(float4 a){
  half4v r;
  r[0]=(_Float16)a.x; r[1]=(_Float16)a.y; r[2]=(_Float16)a.z; r[3]=(_Float16)a.w;
  return r;
}
__device__ __forceinline__ half8 pack8(float4 a, float4 b){
  half8 r;
  r[0]=(_Float16)a.x; r[1]=(_Float16)a.y; r[2]=(_Float16)a.z; r[3]=(_Float16)a.w;
  r[4]=(_Float16)b.x; r[5]=(_Float16)b.y; r[6]=(_Float16)b.z; r[7]=(_Float16)b.w;
  return r;
}

// ---------------------------------------------------------------------------
// Kernel 1: gate table = emb @ Wih.T + bias, per direction.
// Layout: [dir][v][w(8)][hi(4)][g(4)][4] f32  (each (v,w,hi) = 64B contiguous)
// mfma 16x16x16f16 canonical: A/B lane l: m(n)=l&15, k=4*(l>>4)+j.
// C/D: col=l&15, row=4*(l>>4)+reg.  (16x16x32: two K=16 halves, j<4 | j>=4)
__global__ __launch_bounds__(512) void k_table(const float* __restrict__ emb,
    const float* __restrict__ Wih_f, const float* __restrict__ b_f,
    const float* __restrict__ Wih_b, const float* __restrict__ b_b,
    float* __restrict__ table){
  const int dir = blockIdx.x & 1, vt = blockIdx.x >> 1;
  const float* Wih  = dir ? Wih_b : Wih_f;
  const float* bias = dir ? b_b  : b_f;
  const int w = threadIdx.x >> 6, l = threadIdx.x & 63;
  const int lA = l & 15, hi = l >> 4;

  half4v wf[4][8];
#pragma unroll
  for (int g = 0; g < 4; ++g)
#pragma unroll
    for (int kb = 0; kb < 8; ++kb){
      const size_t base = (size_t)(g*128 + 16*w + lA)*128 + kb*16 + 4*hi;
      wf[g][kb] = pack4(*reinterpret_cast<const float4*>(Wih + base));
    }
  const int v0 = vt*16;
  half4v bfr[8];
#pragma unroll
  for (int kb = 0; kb < 8; ++kb){
    const size_t base = (size_t)(v0 + lA)*128 + kb*16 + 4*hi;
    bfr[kb] = pack4(*reinterpret_cast<const float4*>(emb + base));
  }
  f32x4 acc[4];
#pragma unroll
  for (int g = 0; g < 4; ++g)
    acc[g] = *reinterpret_cast<const f32x4*>(bias + g*128 + 16*w + 4*hi);
#pragma unroll
  for (int kb = 0; kb < 8; ++kb)
#pragma unroll
    for (int g = 0; g < 4; ++g)
      acc[g] = __builtin_amdgcn_mfma_f32_16x16x16f16(wf[g][kb], bfr[kb], acc[g], 0, 0, 0);
  float* outp = table + ((((size_t)dir*4096 + v0 + lA)*8 + w)*4 + hi)*16;
#pragma unroll
  for (int g = 0; g < 4; ++g)
    *reinterpret_cast<f32x4*>(outp + g*4) = acc[g];
}

// ---------------------------------------------------------------------------
// LSTM epilogue: c' = sig(f)*c + sig(i)*tanh(g); h = sig(o)*tanh(c')
__device__ __forceinline__ void epi_step(float iv, float fv, float gv, float ov,
                                         float& c, float& h){
  float Ae = __expf(-iv);
  float Be = __expf(2.f*gv);
  float st = (Be - 1.f) * rcpf_((1.f + Ae)*(Be + 1.f));
  float Fe = __expf(-fv);
  float cn = rcpf_(1.f + Fe)*c + st;
  c = cn;
  float Oe = __expf(-ov);
  float Ce = __expf(2.f*cn);
  h = (Ce - 1.f) * rcpf_((1.f + Oe)*(Ce + 1.f));
}

// ---------------------------------------------------------------------------
// Kernel 2: persistent BiLSTM, 16x16x32 MFMA, unroll-2, depth-2 prefetch.
// grid = 8 blocks (dir*4 + chain), 512 threads = 8 waves.
// Wave w: units [16w,16w+16) all gates. hbuf[buf][q][lane][8]: half8 B-frag
// for K-block pair q (k in [32q,32q+32)) read as one ds_read_b128.
__global__ __launch_bounds__(512, 2) void k_lstm(
    const float* __restrict__ Whh_f, const float* __restrict__ Whh_b,
    const int* __restrict__ x, const float* __restrict__ table,
    _Float16* __restrict__ hcat){
  const int dir = blockIdx.x >> 2;
  const int chain = blockIdx.x & 3;
  const float* Whh = dir ? Whh_b : Whh_f;
  const float* tbl = table + (size_t)dir*4096*512;
  const int w  = threadIdx.x >> 6;
  const int l  = threadIdx.x & 63;
  const int lA = l & 15;
  const int hi = l >> 4;

  // K=32 fragments: two K=16 canonical halves packed per half8
  half8 whh[4][4];
#pragma unroll
  for (int g = 0; g < 4; ++g)
#pragma unroll
    for (int q = 0; q < 4; ++q){
      const size_t base = (size_t)(g*128 + 16*w + lA)*128 + q*32 + 4*hi;
      whh[g][q] = pack8(*reinterpret_cast<const float4*>(Whh + base),
                        *reinterpret_cast<const float4*>(Whh + base + 16));
    }

  __shared__ __align__(16) _Float16 hbuf[2][4][64][8];
  reinterpret_cast<int4*>(&hbuf[0][0][0][0])[threadIdx.x] = make_int4(0,0,0,0);
  __syncthreads();

  const int b = chain*16 + lA;
  const int* xrow = x + (size_t)b*T_LEN;
  _Float16* hgbase = hcat + (size_t)b*256 + dir*128 + 16*w + 4*hi;
  // lane's h' (units 16w+4hi..+3) = K-pair q=w>>1, half (w&1)
  _Float16* ldsw0 = &hbuf[0][w>>1][l][4*(w&1)];
  _Float16* ldsw1 = &hbuf[1][w>>1][l][4*(w&1)];
  const int seg = (w*4 + hi)*16;          // lane's 64B segment within a row

  // prologue: depth-2 prefetch
  f32x4 tbA[4], tbB[4];
  int idxA2, idxB2;
  {
    const int i0 = xrow[dir ? 2047 : 0];
    const int i1 = xrow[dir ? 2046 : 1];
    const float* pA = tbl + (size_t)i0*512 + seg;
    const float* pB = tbl + (size_t)i1*512 + seg;
#pragma unroll
    for (int g = 0; g < 4; ++g) tbA[g] = *reinterpret_cast<const f32x4*>(pA + g*4);
#pragma unroll
    for (int g = 0; g < 4; ++g) tbB[g] = *reinterpret_cast<const f32x4*>(pB + g*4);
    idxA2 = xrow[dir ? 2045 : 2];
    idxB2 = xrow[dir ? 2044 : 3];
  }
  float cc0=0.f, cc1=0.f, cc2=0.f, cc3=0.f;

  for (int tt = 0; tt < T_LEN; tt += 2){
    // ================= even step t=tt : read hbuf[0], write hbuf[1] ========
    {
      half8 ah[4];
#pragma unroll
      for (int q = 0; q < 4; ++q)
        ah[q] = *reinterpret_cast<const half8*>(&hbuf[0][q][l][0]);
      f32x4 acc[4];
#pragma unroll
      for (int g = 0; g < 4; ++g)
        acc[g] = __builtin_amdgcn_mfma_f32_16x16x32_f16(whh[g][0], ah[0], tbA[g], 0, 0, 0);
      { // reissue tbA <- gates(t+2)
        const float* pA = tbl + (size_t)idxA2*512 + seg;
#pragma unroll
        for (int g = 0; g < 4; ++g) tbA[g] = *reinterpret_cast<const f32x4*>(pA + g*4);
        const int tn = (tt+4 < T_LEN) ? tt+4 : T_LEN-1;
        idxA2 = xrow[dir ? (T_LEN-1-tn) : tn];
      }
#pragma unroll
      for (int q = 1; q < 4; ++q)
#pragma unroll
        for (int g = 0; g < 4; ++g)
          acc[g] = __builtin_amdgcn_mfma_f32_16x16x32_f16(whh[g][q], ah[q], acc[g], 0, 0, 0);

      float hv0, hv1, hv2, hv3;
      epi_step(acc[0][0], acc[1][0], acc[2][0], acc[3][0], cc0, hv0);
      epi_step(acc[0][1], acc[1][1], acc[2][1], acc[3][1], cc1, hv1);
      epi_step(acc[0][2], acc[1][2], acc[2][2], acc[3][2], cc2, hv2);
      epi_step(acc[0][3], acc[1][3], acc[2][3], acc[3][3], cc3, hv3);
      half4v hp;
      hp[0]=(_Float16)hv0; hp[1]=(_Float16)hv1; hp[2]=(_Float16)hv2; hp[3]=(_Float16)hv3;
      *reinterpret_cast<half4v*>(ldsw1) = hp;
      const int tx = dir ? (T_LEN-1-tt) : tt;
      *reinterpret_cast<half4v*>(hgbase + (size_t)tx*16384) = hp;
      asm volatile("s_waitcnt lgkmcnt(0)" ::: "memory");
      __builtin_amdgcn_sched_barrier(0);
      __builtin_amdgcn_s_barrier();
      __builtin_amdgcn_sched_barrier(0);
    }
    // ================= odd step t=tt+1 : read hbuf[1], write hbuf[0] =======
    {
      half8 ah[4];
#pragma unroll
      for (int q = 0; q < 4; ++q)
        ah[q] = *reinterpret_cast<const half8*>(&hbuf[1][q][l][0]);
      f32x4 acc[4];
#pragma unroll
      for (int g = 0; g < 4; ++g)
        acc[g] = __builtin_amdgcn_mfma_f32_16x16x32_f16(whh[g][0], ah[0], tbB[g], 0, 0, 0);
      { // reissue tbB <- gates(t+3)
        const float* pB = tbl + (size_t)idxB2*512 + seg;
#pragma unroll
        for (int g = 0; g < 4; ++g) tbB[g] = *reinterpret_cast<const f32x4*>(pB + g*4);
        const int tn = (tt+5 < T_LEN) ? tt+5 : T_LEN-1;
        idxB2 = xrow[dir ? (T_LEN-1-tn) : tn];
      }
#pragma unroll
      for (int q = 1; q < 4; ++q)
#pragma unroll
        for (int g = 0; g < 4; ++g)
          acc[g] = __builtin_amdgcn_mfma_f32_16x16x32_f16(whh[g][q], ah[q], acc[g], 0, 0, 0);

      float hv0, hv1, hv2, hv3;
      epi_step(acc[0][0], acc[1][0], acc[2][0], acc[3][0], cc0, hv0);
      epi_step(acc[0][1], acc[1][1], acc[2][1], acc[3][1], cc1, hv1);
      epi_step(acc[0][2], acc[1][2], acc[2][2], acc[3][2], cc2, hv2);
      epi_step(acc[0][3], acc[1][3], acc[2][3], acc[3][3], cc3, hv3);
      half4v hp;
      hp[0]=(_Float16)hv0; hp[1]=(_Float16)hv1; hp[2]=(_Float16)hv2; hp[3]=(_Float16)hv3;
      *reinterpret_cast<half4v*>(ldsw0) = hp;
      const int tx = dir ? (T_LEN-2-tt) : tt+1;
      *reinterpret_cast<half4v*>(hgbase + (size_t)tx*16384) = hp;
      asm volatile("s_waitcnt lgkmcnt(0)" ::: "memory");
      __builtin_amdgcn_sched_barrier(0);
      __builtin_amdgcn_s_barrier();
      __builtin_amdgcn_sched_barrier(0);
    }
  }
}

// ---------------------------------------------------------------------------
// Kernel 3: CRF chunk transition matrices (log-semiring chain product).
__global__ __launch_bounds__(256) void k_crfchunk(const _Float16* __restrict__ hcat,
    const float* __restrict__ fc_w, const float* __restrict__ fc_b,
    const float* __restrict__ trans, float* __restrict__ chunkP){
  const int wv = threadIdx.x >> 6;
  const int l  = threadIdx.x & 63;
  const int task = blockIdx.x*4 + wv;   // k*64 + b
  const int k = task >> 6;
  const int b = task & 63;
  const int i = l >> 3, jc = l & 7;
  float trC[8];
#pragma unroll
  for (int kk = 0; kk < 8; ++kk) trC[kk] = trans[kk*8 + jc];
  const float tii = trans[l];
  float wreg[32];
#pragma unroll
  for (int q = 0; q < 32; ++q) wreg[q] = fc_w[jc*256 + i*32 + q];
  const float fcb = fc_b[jc];
  const int tstart = 1 + k*CHS;
  const int len = (CHS < T_LEN - tstart) ? CHS : (T_LEN - tstart);
  float P = 0.f;
  for (int s = 0; s < len; ++s){
    const int t = tstart + s;
    const _Float16* hp = hcat + ((size_t)t*64 + b)*256 + i*32;
    float dot = 0.f;
#pragma unroll
    for (int q8 = 0; q8 < 4; ++q8){
      half8 hv = *reinterpret_cast<const half8*>(hp + q8*8);
#pragma unroll
      for (int j = 0; j < 8; ++j) dot += (float)hv[j] * wreg[q8*8 + j];
    }
    dot += __shfl_xor(dot, 8);
    dot += __shfl_xor(dot, 16);
    dot += __shfl_xor(dot, 32);
    const float em = fcb + dot;
    if (s == 0){
      P = tii + em;
    } else {
      float v[8];
#pragma unroll
      for (int kk = 0; kk < 8; ++kk) v[kk] = __shfl(P, (l & 56) | kk) + trC[kk];
      float m = v[0];
#pragma unroll
      for (int kk = 1; kk < 8; ++kk) m = fmaxf(m, v[kk]);
      float ss = 0.f;
#pragma unroll
      for (int kk = 0; kk < 8; ++kk) ss += __expf(v[kk] - m);
      P = m + __logf(ss) + em;
    }
  }
  chunkP[(size_t)task*64 + l] = P;
}

// ---------------------------------------------------------------------------
// Kernel 4: fold alpha0 through 128 chunk matrices, LSE with end.
__global__ __launch_bounds__(512) void k_crffinal(const _Float16* __restrict__ hcat,
    const float* __restrict__ fc_w, const float* __restrict__ fc_b,
    const float* __restrict__ trans, const float* __restrict__ startv,
    const float* __restrict__ endv, const float* __restrict__ chunkP,
    float* __restrict__ out){
  const int tid = threadIdx.x;
  const int b = tid >> 3, jc = tid & 7;
  const int l = tid & 63;
  float em = fc_b[jc];
  const _Float16* hp = hcat + (size_t)b*256;   // t = 0
  const float* wr = fc_w + jc*256;
#pragma unroll
  for (int q = 0; q < 32; ++q){
    half8 hv = *reinterpret_cast<const half8*>(hp + q*8);
#pragma unroll
    for (int j = 0; j < 8; ++j) em += (float)hv[j] * wr[q*8 + j];
  }
  float alpha = startv[jc] + em;
  for (int k = 0; k < NCH; ++k){
    const float* pk = chunkP + ((size_t)k*64 + b)*64;
    float v[8];
#pragma unroll
    for (int kk = 0; kk < 8; ++kk) v[kk] = __shfl(alpha, (l & 56) | kk) + pk[kk*8 + jc];
    float m = v[0];
#pragma unroll
    for (int kk = 1; kk < 8; ++kk) m = fmaxf(m, v[kk]);
    float ss = 0.f;
#pragma unroll
    for (int kk = 0; kk < 8; ++kk) ss += __expf(v[kk] - m);
    alpha = m + __logf(ss);
  }
  float vf = alpha + endv[jc];
  float m = vf;
  m = fmaxf(m, __shfl_xor(m, 1));
  m = fmaxf(m, __shfl_xor(m, 2));
  m = fmaxf(m, __shfl_xor(m, 4));
  float e = __expf(vf - m);
  e += __shfl_xor(e, 1);
  e += __shfl_xor(e, 2);
  e += __shfl_xor(e, 4);
  if (jc == 0) out[b] = m + __logf(e);
}

// ---------------------------------------------------------------------------
extern "C" void kernel_launch(void* const* d_in, const int* in_sizes, int n_in,
                              void* d_out, int out_size, void* d_ws, size_t ws_size,
                              hipStream_t stream){
  const int*   x     = (const int*)d_in[0];
  const float* emb   = (const float*)d_in[1];
  const float* Wih_f = (const float*)d_in[2];
  const float* Whh_f = (const float*)d_in[3];
  const float* b_f   = (const float*)d_in[4];
  const float* Wih_b = (const float*)d_in[5];
  const float* Whh_b = (const float*)d_in[6];
  const float* b_b   = (const float*)d_in[7];
  const float* fc_w  = (const float*)d_in[8];
  const float* fc_b  = (const float*)d_in[9];
  const float* trans = (const float*)d_in[10];
  const float* startp= (const float*)d_in[11];
  const float* endp  = (const float*)d_in[12];
  float* out = (float*)d_out;

  const size_t off_tbl  = 0;
  const size_t off_hcat = 16777216;               // 2*4096*512*4
  const size_t off_chk  = 16777216 + 67108864;    // + 2048*64*256*2
  const size_t need     = off_chk + 2097152;      // + 128*64*64*4
  if (ws_size < need){
    (void)hipMemsetAsync(d_out, 0, 64*sizeof(float), stream);
    return;
  }
  float* table  = (float*)((char*)d_ws + off_tbl);
  _Float16* hcat = (_Float16*)((char*)d_ws + off_hcat);
  float* chunkP  = (float*)((char*)d_ws + off_chk);

  k_table<<<512, 512, 0, stream>>>(emb, Wih_f, b_f, Wih_b, b_b, table);
  k_lstm<<<8, 512, 0, stream>>>(Whh_f, Whh_b, x, table, hcat);
  k_crfchunk<<<2048, 256, 0, stream>>>(hcat, fc_w, fc_b, trans, chunkP);
  k_crffinal<<<1, 512, 0, stream>>>(hcat, fc_w, fc_b, trans, startp, endp, chunkP, out);
}